// Round 11
// baseline (88.870 us; speedup 1.0000x reference)
//
#include <hip/hip_runtime.h>
#include <hip/hip_bf16.h>
#include <float.h>
#include <stdint.h>

#define NPTS 4096
#define NB_K 32
#define CAP  256
#define CAPC 320          // per-column capacity (mean 163.8 -> no overflow, r9/r10 verified)

typedef short bf16x8 __attribute__((ext_vector_type(8)));
typedef float f32x4  __attribute__((ext_vector_type(4)));
#define MFMA_BF16 __builtin_amdgcn_mfma_f32_16x16x32_bf16
#define SCHED_FENCE() __builtin_amdgcn_sched_barrier(0)

__device__ __forceinline__ short bf16rne(float f) {
    unsigned u = __float_as_uint(f);
    unsigned r = u + 0x7fffu + ((u >> 16) & 1u);
    return (short)(r >> 16);
}
__device__ __forceinline__ short bfc(float f) {          // HW v_cvt (RNE, finite-safe)
    __hip_bfloat16 h = __float2bfloat16(f);
    return __builtin_bit_cast(short, h);
}

// ---------------------------------------------------------------------------
// Kernel 0 "prep0" (10 blocks): blocks 0-8 = verbatim verified weight pack;
// block 9 zeroes the 100 column counters. (verified r9-r10)
// ---------------------------------------------------------------------------
__global__ __launch_bounds__(256) void prep0_kernel(const float* __restrict__ W1,
                                                    const float* __restrict__ W2,
                                                    const float* __restrict__ W3,
                                                    short* __restrict__ frg,
                                                    unsigned* __restrict__ cnt) {
    const int tid = threadIdx.x;
    if (blockIdx.x == 9) {
        if (tid < 100) cnt[tid] = 0;
        return;
    }
    const int t = blockIdx.x * 256 + tid;
    const int frag = t >> 6, lane = t & 63;
    const int col16 = lane & 15, kg = lane >> 4;
    bf16x8 v;
    if (frag < 12) {                       // W1: natural k (x/rel input order)
        const int s = frag >> 2, n = frag & 3;
        #pragma unroll
        for (int j = 0; j < 8; ++j) {
            const int k = s * 32 + kg * 8 + j;
            v[j] = (k < 67) ? bf16rne(W1[k * 64 + n * 16 + col16]) : (short)0;
        }
    } else if (frag < 20) {                // W2: sigma-permuted rows
        const int s = (frag - 12) >> 2, n = (frag - 12) & 3;
        #pragma unroll
        for (int j = 0; j < 8; ++j) {
            const int k = (2 * s + (j >> 2)) * 16 + kg * 4 + (j & 3);
            v[j] = bf16rne(W2[k * 64 + n * 16 + col16]);
        }
    } else {                               // W3: sigma-permuted rows
        const int s = (frag - 20) >> 3, n = (frag - 20) & 7;
        #pragma unroll
        for (int j = 0; j < 8; ++j) {
            const int k = (2 * s + (j >> 2)) * 16 + kg * 4 + (j & 3);
            v[j] = bf16rne(W3[k * 128 + n * 16 + col16]);
        }
    }
    *(bf16x8*)(frg + (size_t)t * 8) = v;
}

// ---------------------------------------------------------------------------
// Kernel 1 "bin" v2 (64 blocks): LDS histogram -> 25 global atomics/block ->
// ranked scatter; possrt = float4(xyz, idx bits). (verified r10)
// ---------------------------------------------------------------------------
__global__ __launch_bounds__(256) void bin_kernel(const float* __restrict__ pos,
                                                  float4* __restrict__ possrt,
                                                  unsigned* __restrict__ cnt) {
    __shared__ unsigned hist[25];
    __shared__ unsigned base[25];
    const int tid = threadIdx.x;
    const int id = blockIdx.x * 256 + tid;              // 0..16383
    const int g = id >> 12;                             // one graph per block

    if (tid < 25) hist[tid] = 0;
    __syncthreads();

    const float px = pos[(size_t)id * 3 + 0];
    const float py = pos[(size_t)id * 3 + 1];
    const float pz = pos[(size_t)id * 3 + 2];
    int cx = (int)(px * 5.f); if (cx > 4) cx = 4;
    int cy = (int)(py * 5.f); if (cy > 4) cy = 4;
    const int c = cx * 5 + cy;
    const unsigned rank = atomicAdd(&hist[c], 1u);      // LDS atomic
    __syncthreads();

    if (tid < 25) base[tid] = atomicAdd(&cnt[g * 25 + tid], hist[tid]);
    __syncthreads();

    const unsigned slot = base[c] + rank;
    if (slot < CAPC) {
        float4 o;
        o.x = px; o.y = py; o.z = pz;
        o.w = __uint_as_float((unsigned)(id & (NPTS - 1)));
        possrt[(size_t)(g * 25 + c) * CAPC + slot] = o;
    }
}

// ---------------------------------------------------------------------------
// Kernel 2 "knn" v17 -- column-quad shared scan. Wave W -> (col = W%100,
// quad = W/100): 4 consecutive slots of ONE column are this wave's targets.
// All 4 share the column's 3x3 cell neighborhood (cell == R guarantees it
// covers every member's ball) -> ONE scan serves 4 targets (restores and
// doubles r8's amortization; scan tests/target ~1100 vs brute 4096). Scan
// compacts 4 candidate lists simultaneously; then 4x verbatim-verified
// double-exact rank-32 + bitonic sort; nb16 row = g*4096 + stored idx.
// Inactive waves (4q >= count) exit right after the x->bf16 convert.
// ---------------------------------------------------------------------------
__global__ __launch_bounds__(256, 4) void knn_kernel(const float* __restrict__ x,
                                                     const float4* __restrict__ possrt,
                                                     const unsigned* __restrict__ cntArr,
                                                     unsigned short* __restrict__ nb16,
                                                     short* __restrict__ xb) {
    __shared__ int cand[4][4][CAP];        // [wave][target][CAP] = 16 KB
    __shared__ unsigned short nbl[4][32];
    const int tid = threadIdx.x;

    // ---- x -> bf16 (verbatim r8: 2 coalesced floats/thread, needs grid 2048) ----
    {
        const size_t base = ((size_t)blockIdx.x * 256 + tid) * 2;
        const float2 f = *(const float2*)(x + base);
        short2 o; o.x = bfc(f.x); o.y = bfc(f.y);
        *(short2*)(xb + base) = o;
    }

    const int wv = tid >> 6, lane = tid & 63;
    const int W = blockIdx.x * 4 + wv;
    const int col = W % 100;               // g*25 + cx*5 + cy
    const int q = W / 100;                 // quad within column
    int n0 = (int)cntArr[col]; if (n0 > CAPC) n0 = CAPC;
    if (q * 4 >= n0) return;               // inactive (no barriers below -> safe)

    const unsigned long long ltm = (1ull << lane) - 1ull;
    const float RFILT = 0.040001f;
    const double RR = 0.2 * 0.2;
    const unsigned long long INF = ~0ull;

    const int g = col / 25, cell = col % 25, cx = cell / 5, cy = cell % 5;
    const int cxl = cx > 0 ? cx - 1 : 0, cxh = cx < 4 ? cx + 1 : 4;
    const int cyl = cy > 0 ? cy - 1 : 0, cyh = cy < 4 ? cy + 1 : 4;

    // ---- target coords (4 consecutive slots of this column) ----
    float tx[4], ty[4], tz[4];
    int tidx[4]; bool tval[4];
    int tcnt[4] = {0, 0, 0, 0};
    #pragma unroll
    for (int t = 0; t < 4; ++t) {
        const int slot = q * 4 + t;
        tval[t] = slot < n0;
        const float4 tp = possrt[(size_t)col * CAPC + (tval[t] ? slot : 0)];
        tx[t] = tp.x; ty[t] = tp.y; tz[t] = tp.z;
        tidx[t] = (int)__float_as_uint(tp.w);
    }

    // ---- shared 3x3 scan, 4 simultaneous compactions ----
    for (int cx2 = cxl; cx2 <= cxh; ++cx2)
        for (int cy2 = cyl; cy2 <= cyh; ++cy2) {
            const int col2 = g * 25 + cx2 * 5 + cy2;
            int n = (int)cntArr[col2]; if (n > CAPC) n = CAPC;
            const int base = col2 * CAPC;
            for (int s0 = 0; s0 < n; s0 += 64) {
                const int sl = s0 + lane;
                const int li = base + sl;
                bool wt[4] = {false, false, false, false};
                if (sl < n) {
                    const float4 cp = possrt[li];
                    #pragma unroll
                    for (int t = 0; t < 4; ++t) {
                        const float dx = cp.x - tx[t], dy = cp.y - ty[t], dz = cp.z - tz[t];
                        const float d2 = fmaf(dx, dx, fmaf(dy, dy, dz * dz));
                        wt[t] = d2 <= RFILT;
                    }
                }
                #pragma unroll
                for (int t = 0; t < 4; ++t) {
                    const unsigned long long m = __ballot(wt[t]);
                    const int wp = tcnt[t] + __popcll(m & ltm);
                    if (wt[t] && wp < CAP) cand[wv][t][wp] = li;
                    tcnt[t] += __popcll(m);
                }
            }
        }

    // ---- per target: verbatim exact rank-32 + sort + write ----
    for (int t = 0; t < 4; ++t) {
        if (!tval[t]) continue;
        int cnt = tcnt[t]; if (cnt > CAP) cnt = CAP;
        const int* cd = cand[wv][t];
        const double txd = (double)tx[t], tyd = (double)ty[t], tzd = (double)tz[t];

        unsigned long long k0 = INF, k1 = INF, k2 = INF, k3 = INF;
#define LOADK(KS, S)                                                          \
        { const int p = lane + 64 * (S);                                      \
          if (p < cnt) {                                                      \
              const float4 cp = possrt[cd[p]];                                \
              const double ddx = (double)cp.x - txd;                          \
              const double ddy = (double)cp.y - tyd;                          \
              const double ddz = (double)cp.z - tzd;                          \
              const double dd = fma(ddx, ddx, fma(ddy, ddy, ddz * ddz));      \
              if (dd <= RR)                                                   \
                  KS = ((unsigned long long)__double_as_longlong(dd)          \
                        & ~0xfffULL)                                          \
                       | (unsigned long long)__float_as_uint(cp.w);           \
          } }
        LOADK(k0, 0) LOADK(k1, 1) LOADK(k2, 2) LOADK(k3, 3)
#undef LOADK

        const int cnt2 = __popcll(__ballot(k0 != INF)) + __popcll(__ballot(k1 != INF))
                       + __popcll(__ballot(k2 != INF)) + __popcll(__ballot(k3 != INF));

        unsigned long long pivot = 0xFFFFFFFFFFFFFFFEull;
        if (cnt2 > NB_K) {
            unsigned long long lo = 0, hi = 0x3FA5000000000000ull;
            for (int it = 0; it < 70; ++it) {
                const unsigned long long mid = lo + ((hi - lo) >> 1);
                const int c = __popcll(__ballot(k0 <= mid)) + __popcll(__ballot(k1 <= mid))
                            + __popcll(__ballot(k2 <= mid)) + __popcll(__ballot(k3 <= mid));
                if (c == NB_K) { pivot = mid; break; }
                if (c < NB_K) lo = mid + 1; else hi = mid - 1;
            }
        }

        int base = 0;
#define EMIT(KS)                                                              \
        { const bool sel = (KS <= pivot);                                     \
          const unsigned long long m = __ballot(sel);                         \
          const int wp = base + __popcll(m & ltm);                            \
          if (sel && wp < NB_K)                                               \
              nbl[wv][wp] = (unsigned short)(KS & 0xfff);                     \
          base += __popcll(m); }
        EMIT(k0) EMIT(k1) EMIT(k2) EMIT(k3)
#undef EMIT
        if (lane >= base && lane < NB_K)
            nbl[wv][lane] = (unsigned short)0xFFFF;

        // ---- bitonic sort by idx (verified r10; restores ascending order) ----
        unsigned v = (unsigned)nbl[wv][lane & 31];
        #pragma unroll
        for (int k = 2; k <= 32; k <<= 1)
            #pragma unroll
            for (int j = k >> 1; j > 0; j >>= 1) {
                const unsigned o = (unsigned)__shfl_xor((int)v, j);
                const bool lower = (lane & j) == 0;
                const bool up = (lane & k) == 0;
                const unsigned mn = v < o ? v : o;
                const unsigned mx = v < o ? o : v;
                v = (lower == up) ? mn : mx;
            }
        const int gtgt = g * NPTS + tidx[t];
        if (lane < NB_K)
            nb16[(size_t)gtgt * NB_K + lane] = (unsigned short)v;
    }
}

// ---------------------------------------------------------------------------
// Kernel 3 "mlp" v13: VERBATIM r8-verified 2-m-tile sigma MLP (fences,
// (256,4), bf16 pre-converted gather, no spill).
// ---------------------------------------------------------------------------
__global__ __launch_bounds__(256, 4) void mlp_kernel(
    const short* __restrict__ xb, const float* __restrict__ pos, const int* __restrict__ batch,
    const float* __restrict__ b1, const float* __restrict__ b2, const float* __restrict__ b3,
    const unsigned short* __restrict__ nb16, const short* __restrict__ frg,
    float* __restrict__ out) {
    __shared__ short bfr[36 * 64 * 8];            // 36 KB weights (only LDS)

    const int tid = threadIdx.x, wv = tid >> 6, lane = tid & 63;

    for (int i = tid; i < 36 * 64; i += 256)
        *(bf16x8*)(bfr + (size_t)i * 8) = *(const bf16x8*)(frg + (size_t)i * 8);
    __syncthreads();   // only barrier: weights visible

    const int c0 = lane & 15, kg = lane >> 4, rlow = kg * 4;
    const int wbase = blockIdx.x * 4 + wv;        // wave id; 4 consecutive targets
    const int gb = (wbase * 4) & ~(NPTS - 1);     // 4-aligned -> single graph

    int nvAll[2];
    #pragma unroll
    for (int q = 0; q < 2; ++q)
        nvAll[q] = (int)nb16[(size_t)(wbase * 4 + q * 2 + (lane >> 5)) * 32 + (lane & 31)];

    for (int p = 0; p < 4; ++p) {
        const int tgt = wbase * 4 + p;
        const int nv = nvAll[p >> 1];
        const unsigned long long bm = __ballot(nv != 0xFFFF);
        const unsigned vmask = (p & 1) ? (unsigned)(bm >> 32) : (unsigned)bm;

        int jrow[2];
        #pragma unroll
        for (int mm = 0; mm < 2; ++mm) {
            const int j = __shfl(nv, (p & 1) * 32 + mm * 16 + c0);
            jrow[mm] = (j == 0xFFFF) ? 0 : j;
        }

        // ---- gather X (bf16 rows: ONE 16B load per fragment) ----
        bf16x8 X1[2][3];
        #pragma unroll
        for (int mm = 0; mm < 2; ++mm) {
            const short* xr = xb + (size_t)(gb + jrow[mm]) * 64;
            #pragma unroll
            for (int s = 0; s < 2; ++s)
                X1[mm][s] = *(const bf16x8*)(xr + s * 32 + kg * 8);
            bf16x8 a = {0, 0, 0, 0, 0, 0, 0, 0};
            if (kg == 0) {
                const float* pj = pos + (size_t)(gb + jrow[mm]) * 3;
                const float* pi = pos + (size_t)tgt * 3;
                a[0] = bfc(pj[0] - pi[0]);
                a[1] = bfc(pj[1] - pi[1]);
                a[2] = bfc(pj[2] - pi[2]);
            }
            X1[mm][2] = a;
        }

        // ---- layer 1 (swapped): h1 channel = nt*16 + kg*4 + r, col = neighbor ----
        bf16x8 B2[2][2];
        #pragma unroll
        for (int nt = 0; nt < 4; ++nt) {
            const float4 bb = *(const float4*)(b1 + nt * 16 + rlow);
            f32x4 acc[2];
            acc[0] = acc[1] = f32x4{bb.x, bb.y, bb.z, bb.w};
            #pragma unroll
            for (int s = 0; s < 3; ++s) {
                const bf16x8 Wf = *(const bf16x8*)(bfr + (size_t)((s * 4 + nt) * 64 + lane) * 8);
                #pragma unroll
                for (int mm = 0; mm < 2; ++mm)
                    acc[mm] = MFMA_BF16(Wf, X1[mm][s], acc[mm], 0, 0, 0);
            }
            #pragma unroll
            for (int mm = 0; mm < 2; ++mm)
                #pragma unroll
                for (int r = 0; r < 4; ++r)
                    B2[mm][nt >> 1][(nt & 1) * 4 + r] = bfc(fmaxf(acc[mm][r], 0.f));
            SCHED_FENCE();   // bound live set: one nt's Wf + acc in flight
        }

        // ---- layer 2 (swapped, sigma-packed W2) ----
        bf16x8 A3[2][2];
        #pragma unroll
        for (int nt = 0; nt < 4; ++nt) {
            const float4 bb = *(const float4*)(b2 + nt * 16 + rlow);
            f32x4 acc[2];
            acc[0] = acc[1] = f32x4{bb.x, bb.y, bb.z, bb.w};
            #pragma unroll
            for (int s = 0; s < 2; ++s) {
                const bf16x8 Wf = *(const bf16x8*)(bfr + (size_t)((12 + s * 4 + nt) * 64 + lane) * 8);
                #pragma unroll
                for (int mm = 0; mm < 2; ++mm)
                    acc[mm] = MFMA_BF16(Wf, B2[mm][s], acc[mm], 0, 0, 0);
            }
            #pragma unroll
            for (int mm = 0; mm < 2; ++mm)
                #pragma unroll
                for (int r = 0; r < 4; ++r)
                    A3[mm][nt >> 1][(nt & 1) * 4 + r] = bfc(fmaxf(acc[mm][r], 0.f));
            SCHED_FENCE();
        }

        // ---- layer 3 (un-swapped) + masked max ----
        #pragma unroll
        for (int n = 0; n < 8; ++n) {
            const float bv = b3[n * 16 + c0];
            f32x4 acc[2];
            acc[0] = acc[1] = f32x4{bv, bv, bv, bv};
            #pragma unroll
            for (int s = 0; s < 2; ++s) {
                const bf16x8 Bf = *(const bf16x8*)(bfr + (size_t)((20 + s * 8 + n) * 64 + lane) * 8);
                #pragma unroll
                for (int mm = 0; mm < 2; ++mm)
                    acc[mm] = MFMA_BF16(A3[mm][s], Bf, acc[mm], 0, 0, 0);
            }
            float v = 0.f;
            #pragma unroll
            for (int mm = 0; mm < 2; ++mm)
                #pragma unroll
                for (int r = 0; r < 4; ++r) {
                    const int row = mm * 16 + rlow + r;
                    const float h = fmaxf(acc[mm][r], 0.f);
                    v = fmaxf(v, ((vmask >> row) & 1u) ? h : 0.f);
                }
            v = fmaxf(v, __shfl_xor(v, 16));
            v = fmaxf(v, __shfl_xor(v, 32));
            if (lane < 16) out[(size_t)tgt * 128 + n * 16 + lane] = v;
            SCHED_FENCE();   // bound live set: one n's Bf + acc in flight
        }

        // ---- passthrough ----
        if (lane < 3)  out[2097152 + (size_t)tgt * 3 + lane] = pos[(size_t)tgt * 3 + lane];
        if (lane == 3) out[2146304 + tgt] = (float)batch[tgt];
    }
}

extern "C" void kernel_launch(void* const* d_in, const int* in_sizes, int n_in,
                              void* d_out, int out_size, void* d_ws, size_t ws_size,
                              hipStream_t stream) {
    const float* x   = (const float*)d_in[0];
    const float* pos = (const float*)d_in[1];
    const int* batch = (const int*)d_in[2];
    const float* W1  = (const float*)d_in[3];
    const float* b1  = (const float*)d_in[4];
    const float* W2  = (const float*)d_in[5];
    const float* b2  = (const float*)d_in[6];
    const float* W3  = (const float*)d_in[7];
    const float* b3  = (const float*)d_in[8];
    float* out = (float*)d_out;

    char* ws = (char*)d_ws;
    short* xb            = (short*)ws;                            // 2 MiB
    unsigned short* nb16 = (unsigned short*)(ws + (2 << 20));     // 1 MiB
    short* frg           = (short*)(ws + (3 << 20));              // 36 KiB
    unsigned* cnt        = (unsigned*)(ws + (3 << 20) + (64 << 10));   // 400 B
    float4* possrt       = (float4*)(ws + (3 << 20) + (128 << 10));    // 500 KiB

    hipLaunchKernelGGL(prep0_kernel, dim3(10), dim3(256), 0, stream, W1, W2, W3, frg, cnt);
    hipLaunchKernelGGL(bin_kernel, dim3(64), dim3(256), 0, stream, pos, possrt, cnt);
    hipLaunchKernelGGL(knn_kernel, dim3(2048), dim3(256), 0, stream,
                       x, possrt, cnt, nb16, xb);
    hipLaunchKernelGGL(mlp_kernel, dim3(1024), dim3(256), 0, stream,
                       xb, pos, batch, b1, b2, b3, nb16, frg, out);
}

// Round 12
// 82.482 us; speedup vs baseline: 1.0774x; 1.0774x over previous
//
#include <hip/hip_runtime.h>
#include <hip/hip_bf16.h>
#include <float.h>
#include <stdint.h>

#define NPTS 4096
#define NB_K 32
#define CAP  256

typedef short bf16x8 __attribute__((ext_vector_type(8)));
typedef float f32x4  __attribute__((ext_vector_type(4)));
#define MFMA_BF16 __builtin_amdgcn_mfma_f32_16x16x32_bf16
#define SCHED_FENCE() __builtin_amdgcn_sched_barrier(0)

__device__ __forceinline__ short bf16rne(float f) {
    unsigned u = __float_as_uint(f);
    unsigned r = u + 0x7fffu + ((u >> 16) & 1u);
    return (short)(r >> 16);
}
__device__ __forceinline__ short bfc(float f) {          // HW v_cvt (RNE, finite-safe)
    __hip_bfloat16 h = __float2bfloat16(f);
    return __builtin_bit_cast(short, h);
}

// ---------------------------------------------------------------------------
// Kernel A v18: r8's verified prep+brute-force knn with FOUR targets/wave
// (1024 blocks x 4 waves x 4 targets). The 4096-point scan pass is shared by
// 4 targets instead of 2: total scan issue halves; per-pair math, candidate
// compaction, exact double rank-32, and ascending-index nb16 output are
// byte-identical to r8 (binned variants r9-r11 all regressed -- reverted).
//  - all blocks: x -> bf16 (4 coalesced floats/thread over 1024 blocks)
//  - blocks 0-8: verbatim sigma weight pack
// ---------------------------------------------------------------------------
__global__ __launch_bounds__(256, 4) void knn_kernel(
    const float* __restrict__ x, const float* __restrict__ pos,
    const float* __restrict__ W1, const float* __restrict__ W2, const float* __restrict__ W3,
    unsigned short* __restrict__ nb16, short* __restrict__ frg, short* __restrict__ xb) {
    __shared__ int cand[4][4][CAP];        // [wave][target][CAP] = 16 KB
    const int tid = threadIdx.x;

    // ---- x -> bf16 (1,048,576 elems / 262,144 threads = 4 each) ----
    {
        const size_t base = ((size_t)blockIdx.x * 256 + tid) * 4;
        const float4 f = *(const float4*)(x + base);
        short4 o;
        o.x = bfc(f.x); o.y = bfc(f.y); o.z = bfc(f.z); o.w = bfc(f.w);
        *(short4*)(xb + base) = o;
    }

    // ---- weight pack (blocks 0-8 cover t = 0..2303, verbatim verified) ----
    if (blockIdx.x < 9) {
        const int t = blockIdx.x * 256 + tid;
        const int frag = t >> 6, lane = t & 63;
        const int col16 = lane & 15, kg = lane >> 4;
        bf16x8 v;
        if (frag < 12) {                       // W1: natural k (x/rel input order)
            const int s = frag >> 2, n = frag & 3;
            #pragma unroll
            for (int j = 0; j < 8; ++j) {
                const int k = s * 32 + kg * 8 + j;
                v[j] = (k < 67) ? bf16rne(W1[k * 64 + n * 16 + col16]) : (short)0;
            }
        } else if (frag < 20) {                // W2: sigma-permuted rows
            const int s = (frag - 12) >> 2, n = (frag - 12) & 3;
            #pragma unroll
            for (int j = 0; j < 8; ++j) {
                const int k = (2 * s + (j >> 2)) * 16 + kg * 4 + (j & 3);
                v[j] = bf16rne(W2[k * 64 + n * 16 + col16]);
            }
        } else {                               // W3: sigma-permuted rows
            const int s = (frag - 20) >> 3, n = (frag - 20) & 7;
            #pragma unroll
            for (int j = 0; j < 8; ++j) {
                const int k = (2 * s + (j >> 2)) * 16 + kg * 4 + (j & 3);
                v[j] = bf16rne(W3[k * 128 + n * 16 + col16]);
            }
        }
        *(bf16x8*)(frg + (size_t)t * 8) = v;
    }

    // ---- brute-force scan, 4 targets share each point load ----
    const int wv = tid >> 6, lane = tid & 63;
    const int tgt0 = (blockIdx.x * 4 + wv) * 4;
    const int gb = tgt0 & ~(NPTS - 1);         // 4-aligned -> single graph
    const unsigned long long ltm = (1ull << lane) - 1ull;
    const float RFILT = 0.040001f;

    float tx[4], ty[4], tz[4];
    #pragma unroll
    for (int t = 0; t < 4; ++t) {
        tx[t] = pos[(size_t)(tgt0 + t) * 3 + 0];
        ty[t] = pos[(size_t)(tgt0 + t) * 3 + 1];
        tz[t] = pos[(size_t)(tgt0 + t) * 3 + 2];
    }

    int cnt[4] = {0, 0, 0, 0};
    for (int c0 = 0; c0 < NPTS; c0 += 64) {
        const int j = c0 + lane;
        const float* pp = pos + (size_t)(gb + j) * 3;
        const float px = pp[0], py = pp[1], pz = pp[2];
        #pragma unroll
        for (int t = 0; t < 4; ++t) {
            const float dx = px - tx[t], dy = py - ty[t], dz = pz - tz[t];
            const float d2 = fmaf(dx, dx, fmaf(dy, dy, dz * dz));
            const bool want = d2 <= RFILT;
            const unsigned long long m = __ballot(want);
            const int wp = cnt[t] + __popcll(m & ltm);
            if (want && wp < CAP) cand[wv][t][wp] = j;
            cnt[t] += __popcll(m);
        }
    }

    // ---- exact double-precision rank-32 per target (verbatim r8 math) ----
    const double RR = 0.2 * 0.2;
    const unsigned long long INF = ~0ull;

    for (int t = 0; t < 4; ++t) {
        const int tgt = tgt0 + t;
        int cntT = cnt[t]; if (cntT > CAP) cntT = CAP;
        const int* cd = cand[wv][t];
        const double txd = (double)pos[(size_t)tgt * 3 + 0];
        const double tyd = (double)pos[(size_t)tgt * 3 + 1];
        const double tzd = (double)pos[(size_t)tgt * 3 + 2];

        unsigned long long k0 = INF, k1 = INF, k2 = INF, k3 = INF;
#define LOADK(KS, S)                                                          \
        { const int p = lane + 64 * (S);                                      \
          if (p < cntT) {                                                     \
              const int ci = cd[p];                                           \
              const float* cp = pos + (size_t)(gb + ci) * 3;                  \
              const double ddx = (double)cp[0] - txd;                         \
              const double ddy = (double)cp[1] - tyd;                         \
              const double ddz = (double)cp[2] - tzd;                         \
              const double dd = fma(ddx, ddx, fma(ddy, ddy, ddz * ddz));      \
              if (dd <= RR)                                                   \
                  KS = ((unsigned long long)__double_as_longlong(dd)          \
                        & ~0xfffULL) | (unsigned long long)ci;                \
          } }
        LOADK(k0, 0) LOADK(k1, 1) LOADK(k2, 2) LOADK(k3, 3)
#undef LOADK

        const int cnt2 = __popcll(__ballot(k0 != INF)) + __popcll(__ballot(k1 != INF))
                       + __popcll(__ballot(k2 != INF)) + __popcll(__ballot(k3 != INF));

        unsigned long long pivot = 0xFFFFFFFFFFFFFFFEull;
        if (cnt2 > NB_K) {
            unsigned long long lo = 0, hi = 0x3FA5000000000000ull;
            for (int it = 0; it < 70; ++it) {
                const unsigned long long mid = lo + ((hi - lo) >> 1);
                const int c = __popcll(__ballot(k0 <= mid)) + __popcll(__ballot(k1 <= mid))
                            + __popcll(__ballot(k2 <= mid)) + __popcll(__ballot(k3 <= mid));
                if (c == NB_K) { pivot = mid; break; }
                if (c < NB_K) lo = mid + 1; else hi = mid - 1;
            }
        }

        int base = 0;
#define EMIT(KS)                                                              \
        { const bool sel = (KS <= pivot);                                     \
          const unsigned long long m = __ballot(sel);                         \
          const int wp = base + __popcll(m & ltm);                            \
          if (sel && wp < NB_K)                                               \
              nb16[(size_t)tgt * NB_K + wp] = (unsigned short)(KS & 0xfff);   \
          base += __popcll(m); }
        EMIT(k0) EMIT(k1) EMIT(k2) EMIT(k3)
#undef EMIT
        if (lane >= base && lane < NB_K)
            nb16[(size_t)tgt * NB_K + lane] = (unsigned short)0xFFFF;
    }
}

// ---------------------------------------------------------------------------
// Kernel B v13: VERBATIM r8-verified 2-m-tile sigma MLP (fences, (256,4),
// bf16 pre-converted gather, no spill).
// ---------------------------------------------------------------------------
__global__ __launch_bounds__(256, 4) void mlp_kernel(
    const short* __restrict__ xb, const float* __restrict__ pos, const int* __restrict__ batch,
    const float* __restrict__ b1, const float* __restrict__ b2, const float* __restrict__ b3,
    const unsigned short* __restrict__ nb16, const short* __restrict__ frg,
    float* __restrict__ out) {
    __shared__ short bfr[36 * 64 * 8];            // 36 KB weights (only LDS)

    const int tid = threadIdx.x, wv = tid >> 6, lane = tid & 63;

    for (int i = tid; i < 36 * 64; i += 256)
        *(bf16x8*)(bfr + (size_t)i * 8) = *(const bf16x8*)(frg + (size_t)i * 8);
    __syncthreads();   // only barrier: weights visible

    const int c0 = lane & 15, kg = lane >> 4, rlow = kg * 4;
    const int wbase = blockIdx.x * 4 + wv;        // wave id; 4 consecutive targets
    const int gb = (wbase * 4) & ~(NPTS - 1);     // 4-aligned -> single graph

    int nvAll[2];
    #pragma unroll
    for (int q = 0; q < 2; ++q)
        nvAll[q] = (int)nb16[(size_t)(wbase * 4 + q * 2 + (lane >> 5)) * 32 + (lane & 31)];

    for (int p = 0; p < 4; ++p) {
        const int tgt = wbase * 4 + p;
        const int nv = nvAll[p >> 1];
        const unsigned long long bm = __ballot(nv != 0xFFFF);
        const unsigned vmask = (p & 1) ? (unsigned)(bm >> 32) : (unsigned)bm;

        int jrow[2];
        #pragma unroll
        for (int mm = 0; mm < 2; ++mm) {
            const int j = __shfl(nv, (p & 1) * 32 + mm * 16 + c0);
            jrow[mm] = (j == 0xFFFF) ? 0 : j;
        }

        // ---- gather X (bf16 rows: ONE 16B load per fragment) ----
        bf16x8 X1[2][3];
        #pragma unroll
        for (int mm = 0; mm < 2; ++mm) {
            const short* xr = xb + (size_t)(gb + jrow[mm]) * 64;
            #pragma unroll
            for (int s = 0; s < 2; ++s)
                X1[mm][s] = *(const bf16x8*)(xr + s * 32 + kg * 8);
            bf16x8 a = {0, 0, 0, 0, 0, 0, 0, 0};
            if (kg == 0) {
                const float* pj = pos + (size_t)(gb + jrow[mm]) * 3;
                const float* pi = pos + (size_t)tgt * 3;
                a[0] = bfc(pj[0] - pi[0]);
                a[1] = bfc(pj[1] - pi[1]);
                a[2] = bfc(pj[2] - pi[2]);
            }
            X1[mm][2] = a;
        }

        // ---- layer 1 (swapped): h1 channel = nt*16 + kg*4 + r, col = neighbor ----
        bf16x8 B2[2][2];
        #pragma unroll
        for (int nt = 0; nt < 4; ++nt) {
            const float4 bb = *(const float4*)(b1 + nt * 16 + rlow);
            f32x4 acc[2];
            acc[0] = acc[1] = f32x4{bb.x, bb.y, bb.z, bb.w};
            #pragma unroll
            for (int s = 0; s < 3; ++s) {
                const bf16x8 Wf = *(const bf16x8*)(bfr + (size_t)((s * 4 + nt) * 64 + lane) * 8);
                #pragma unroll
                for (int mm = 0; mm < 2; ++mm)
                    acc[mm] = MFMA_BF16(Wf, X1[mm][s], acc[mm], 0, 0, 0);
            }
            #pragma unroll
            for (int mm = 0; mm < 2; ++mm)
                #pragma unroll
                for (int r = 0; r < 4; ++r)
                    B2[mm][nt >> 1][(nt & 1) * 4 + r] = bfc(fmaxf(acc[mm][r], 0.f));
            SCHED_FENCE();   // bound live set: one nt's Wf + acc in flight
        }

        // ---- layer 2 (swapped, sigma-packed W2) ----
        bf16x8 A3[2][2];
        #pragma unroll
        for (int nt = 0; nt < 4; ++nt) {
            const float4 bb = *(const float4*)(b2 + nt * 16 + rlow);
            f32x4 acc[2];
            acc[0] = acc[1] = f32x4{bb.x, bb.y, bb.z, bb.w};
            #pragma unroll
            for (int s = 0; s < 2; ++s) {
                const bf16x8 Wf = *(const bf16x8*)(bfr + (size_t)((12 + s * 4 + nt) * 64 + lane) * 8);
                #pragma unroll
                for (int mm = 0; mm < 2; ++mm)
                    acc[mm] = MFMA_BF16(Wf, B2[mm][s], acc[mm], 0, 0, 0);
            }
            #pragma unroll
            for (int mm = 0; mm < 2; ++mm)
                #pragma unroll
                for (int r = 0; r < 4; ++r)
                    A3[mm][nt >> 1][(nt & 1) * 4 + r] = bfc(fmaxf(acc[mm][r], 0.f));
            SCHED_FENCE();
        }

        // ---- layer 3 (un-swapped) + masked max ----
        #pragma unroll
        for (int n = 0; n < 8; ++n) {
            const float bv = b3[n * 16 + c0];
            f32x4 acc[2];
            acc[0] = acc[1] = f32x4{bv, bv, bv, bv};
            #pragma unroll
            for (int s = 0; s < 2; ++s) {
                const bf16x8 Bf = *(const bf16x8*)(bfr + (size_t)((20 + s * 8 + n) * 64 + lane) * 8);
                #pragma unroll
                for (int mm = 0; mm < 2; ++mm)
                    acc[mm] = MFMA_BF16(A3[mm][s], Bf, acc[mm], 0, 0, 0);
            }
            float v = 0.f;
            #pragma unroll
            for (int mm = 0; mm < 2; ++mm)
                #pragma unroll
                for (int r = 0; r < 4; ++r) {
                    const int row = mm * 16 + rlow + r;
                    const float h = fmaxf(acc[mm][r], 0.f);
                    v = fmaxf(v, ((vmask >> row) & 1u) ? h : 0.f);
                }
            v = fmaxf(v, __shfl_xor(v, 16));
            v = fmaxf(v, __shfl_xor(v, 32));
            if (lane < 16) out[(size_t)tgt * 128 + n * 16 + lane] = v;
            SCHED_FENCE();   // bound live set: one n's Bf + acc in flight
        }

        // ---- passthrough ----
        if (lane < 3)  out[2097152 + (size_t)tgt * 3 + lane] = pos[(size_t)tgt * 3 + lane];
        if (lane == 3) out[2146304 + tgt] = (float)batch[tgt];
    }
}

extern "C" void kernel_launch(void* const* d_in, const int* in_sizes, int n_in,
                              void* d_out, int out_size, void* d_ws, size_t ws_size,
                              hipStream_t stream) {
    const float* x   = (const float*)d_in[0];
    const float* pos = (const float*)d_in[1];
    const int* batch = (const int*)d_in[2];
    const float* W1  = (const float*)d_in[3];
    const float* b1  = (const float*)d_in[4];
    const float* W2  = (const float*)d_in[5];
    const float* b2  = (const float*)d_in[6];
    const float* W3  = (const float*)d_in[7];
    const float* b3  = (const float*)d_in[8];
    float* out = (float*)d_out;

    short* xb = (short*)d_ws;                                     // 2 MiB bf16 x
    unsigned short* nb16 = (unsigned short*)((char*)d_ws + (2 << 20)); // 1 MiB
    short* frg = (short*)((char*)d_ws + (3 << 20));               // 36 KiB

    hipLaunchKernelGGL(knn_kernel, dim3(1024), dim3(256), 0, stream,
                       x, pos, W1, W2, W3, nb16, frg, xb);
    hipLaunchKernelGGL(mlp_kernel, dim3(1024), dim3(256), 0, stream,
                       xb, pos, batch, b1, b2, b3, nb16, frg, out);
}

// Round 14
// 77.500 us; speedup vs baseline: 1.1467x; 1.0643x over previous
//
#include <hip/hip_runtime.h>
#include <hip/hip_bf16.h>
#include <float.h>
#include <stdint.h>

#define NPTS 4096
#define NB_K 32
#define CAP  256

typedef short bf16x8 __attribute__((ext_vector_type(8)));
typedef float f32x4  __attribute__((ext_vector_type(4)));
#define MFMA_BF16 __builtin_amdgcn_mfma_f32_16x16x32_bf16
#define SCHED_FENCE() __builtin_amdgcn_sched_barrier(0)

__device__ __forceinline__ short bf16rne(float f) {
    unsigned u = __float_as_uint(f);
    unsigned r = u + 0x7fffu + ((u >> 16) & 1u);
    return (short)(r >> 16);
}
__device__ __forceinline__ short bfc(float f) {          // HW v_cvt (RNE, finite-safe)
    __hip_bfloat16 h = __float2bfloat16(f);
    return __builtin_bit_cast(short, h);
}

// ---------------------------------------------------------------------------
// Kernel A (r8-verified, 46.7us): prep + exact radius-ball top-K.
//  - all 2048 blocks: convert their 512-float slice of x to bf16 (xb) --
//    2 floats/thread, coalesced, overlaps the knn latency chains.
//  - blocks 0-8: additionally pack W1/W2/W3 into sigma-ordered bf16 frags.
//  - knn body: verbatim rank-32 pivot search, 2 targets/wave (measured
//    optimum: r12 4-tgt/wave lost TLP; binned r9-r11 all regressed net).
// Determinism audit (r13): no atomics, no read-before-write of persistent
// state, unique writer per output element, all outputs fully rewritten
// every call.
// ---------------------------------------------------------------------------
__global__ __launch_bounds__(256, 4) void knn_kernel(
    const float* __restrict__ x, const float* __restrict__ pos,
    const float* __restrict__ W1, const float* __restrict__ W2, const float* __restrict__ W3,
    unsigned short* __restrict__ nb16, short* __restrict__ frg, short* __restrict__ xb) {
    __shared__ int cand[8][CAP];
    const int tid = threadIdx.x;

    // ---- x -> bf16 (1,048,576 elems / 524,288 threads = 2 each) ----
    {
        const size_t base = ((size_t)blockIdx.x * 256 + tid) * 2;
        const float2 f = *(const float2*)(x + base);
        short2 o; o.x = bfc(f.x); o.y = bfc(f.y);
        *(short2*)(xb + base) = o;
    }

    // ---- weight pack (blocks 0-8 cover t = 0..2303) ----
    if (blockIdx.x < 9) {
        const int t = blockIdx.x * 256 + tid;
        const int frag = t >> 6, lane = t & 63;
        const int col16 = lane & 15, kg = lane >> 4;
        bf16x8 v;
        if (frag < 12) {                       // W1: natural k (x/rel input order)
            const int s = frag >> 2, n = frag & 3;
            #pragma unroll
            for (int j = 0; j < 8; ++j) {
                const int k = s * 32 + kg * 8 + j;
                v[j] = (k < 67) ? bf16rne(W1[k * 64 + n * 16 + col16]) : (short)0;
            }
        } else if (frag < 20) {                // W2: sigma-permuted rows
            const int s = (frag - 12) >> 2, n = (frag - 12) & 3;
            #pragma unroll
            for (int j = 0; j < 8; ++j) {
                const int k = (2 * s + (j >> 2)) * 16 + kg * 4 + (j & 3);
                v[j] = bf16rne(W2[k * 64 + n * 16 + col16]);
            }
        } else {                               // W3: sigma-permuted rows
            const int s = (frag - 20) >> 3, n = (frag - 20) & 7;
            #pragma unroll
            for (int j = 0; j < 8; ++j) {
                const int k = (2 * s + (j >> 2)) * 16 + kg * 4 + (j & 3);
                v[j] = bf16rne(W3[k * 128 + n * 16 + col16]);
            }
        }
        *(bf16x8*)(frg + (size_t)t * 8) = v;
    }

    // ---- knn body (verbatim, verified) ----
    const int wv = tid >> 6, lane = tid & 63;
    const int tgtA = (blockIdx.x * 4 + wv) * 2;
    const int gb = tgtA & ~(NPTS - 1);
    const unsigned long long ltm = (1ull << lane) - 1ull;

    const float tAx = pos[(size_t)tgtA * 3 + 0];
    const float tAy = pos[(size_t)tgtA * 3 + 1];
    const float tAz = pos[(size_t)tgtA * 3 + 2];
    const float tBx = pos[(size_t)(tgtA + 1) * 3 + 0];
    const float tBy = pos[(size_t)(tgtA + 1) * 3 + 1];
    const float tBz = pos[(size_t)(tgtA + 1) * 3 + 2];
    const float RFILT = 0.040001f;

    int cntA = 0, cntB = 0;
    for (int c0 = 0; c0 < NPTS; c0 += 64) {
        const int j = c0 + lane;
        const float* pp = pos + (size_t)(gb + j) * 3;
        const float px = pp[0], py = pp[1], pz = pp[2];
        {
            const float dx = px - tAx, dy = py - tAy, dz = pz - tAz;
            const float d2 = fmaf(dx, dx, fmaf(dy, dy, dz * dz));
            const bool want = d2 <= RFILT;
            const unsigned long long m = __ballot(want);
            const int wp = cntA + __popcll(m & ltm);
            if (want && wp < CAP) cand[wv * 2][wp] = j;
            cntA += __popcll(m);
        }
        {
            const float dx = px - tBx, dy = py - tBy, dz = pz - tBz;
            const float d2 = fmaf(dx, dx, fmaf(dy, dy, dz * dz));
            const bool want = d2 <= RFILT;
            const unsigned long long m = __ballot(want);
            const int wp = cntB + __popcll(m & ltm);
            if (want && wp < CAP) cand[wv * 2 + 1][wp] = j;
            cntB += __popcll(m);
        }
    }
    if (cntA > CAP) cntA = CAP;
    if (cntB > CAP) cntB = CAP;

    const double RR = 0.2 * 0.2;
    const unsigned long long INF = ~0ull;

    for (int t = 0; t < 2; ++t) {
        const int tgt = tgtA + t;
        const int cnt = t ? cntB : cntA;
        const int* cd = cand[wv * 2 + t];
        const double txd = (double)pos[(size_t)tgt * 3 + 0];
        const double tyd = (double)pos[(size_t)tgt * 3 + 1];
        const double tzd = (double)pos[(size_t)tgt * 3 + 2];

        unsigned long long k0 = INF, k1 = INF, k2 = INF, k3 = INF;
#define LOADK(KS, S)                                                          \
        { const int p = lane + 64 * (S);                                      \
          if (p < cnt) {                                                      \
              const int ci = cd[p];                                           \
              const float* cp = pos + (size_t)(gb + ci) * 3;                  \
              const double ddx = (double)cp[0] - txd;                         \
              const double ddy = (double)cp[1] - tyd;                         \
              const double ddz = (double)cp[2] - tzd;                         \
              const double dd = fma(ddx, ddx, fma(ddy, ddy, ddz * ddz));      \
              if (dd <= RR)                                                   \
                  KS = ((unsigned long long)__double_as_longlong(dd)          \
                        & ~0xfffULL) | (unsigned long long)ci;                \
          } }
        LOADK(k0, 0) LOADK(k1, 1) LOADK(k2, 2) LOADK(k3, 3)
#undef LOADK

        const int cnt2 = __popcll(__ballot(k0 != INF)) + __popcll(__ballot(k1 != INF))
                       + __popcll(__ballot(k2 != INF)) + __popcll(__ballot(k3 != INF));

        unsigned long long pivot = 0xFFFFFFFFFFFFFFFEull;
        if (cnt2 > NB_K) {
            unsigned long long lo = 0, hi = 0x3FA5000000000000ull;
            for (int it = 0; it < 70; ++it) {
                const unsigned long long mid = lo + ((hi - lo) >> 1);
                const int c = __popcll(__ballot(k0 <= mid)) + __popcll(__ballot(k1 <= mid))
                            + __popcll(__ballot(k2 <= mid)) + __popcll(__ballot(k3 <= mid));
                if (c == NB_K) { pivot = mid; break; }
                if (c < NB_K) lo = mid + 1; else hi = mid - 1;
            }
        }

        int base = 0;
#define EMIT(KS)                                                              \
        { const bool sel = (KS <= pivot);                                     \
          const unsigned long long m = __ballot(sel);                         \
          const int wp = base + __popcll(m & ltm);                            \
          if (sel && wp < NB_K)                                               \
              nb16[(size_t)tgt * NB_K + wp] = (unsigned short)(KS & 0xfff);   \
          base += __popcll(m); }
        EMIT(k0) EMIT(k1) EMIT(k2) EMIT(k3)
#undef EMIT
        if (lane >= base && lane < NB_K)
            nb16[(size_t)tgt * NB_K + lane] = (unsigned short)0xFFFF;
    }
}

// ---------------------------------------------------------------------------
// Kernel B (r8-verified): 2-m-tile sigma MLP -- all-register layer
// transitions (swapped MFMA + sigma-packed W2/W3), sched fences bounding the
// live set, (256,4) no-spill, bf16 pre-converted gather (one 16B load per
// X1 fragment).
// ---------------------------------------------------------------------------
__global__ __launch_bounds__(256, 4) void mlp_kernel(
    const short* __restrict__ xb, const float* __restrict__ pos, const int* __restrict__ batch,
    const float* __restrict__ b1, const float* __restrict__ b2, const float* __restrict__ b3,
    const unsigned short* __restrict__ nb16, const short* __restrict__ frg,
    float* __restrict__ out) {
    __shared__ short bfr[36 * 64 * 8];            // 36 KB weights (only LDS)

    const int tid = threadIdx.x, wv = tid >> 6, lane = tid & 63;

    for (int i = tid; i < 36 * 64; i += 256)
        *(bf16x8*)(bfr + (size_t)i * 8) = *(const bf16x8*)(frg + (size_t)i * 8);
    __syncthreads();   // only barrier: weights visible

    const int c0 = lane & 15, kg = lane >> 4, rlow = kg * 4;
    const int wbase = blockIdx.x * 4 + wv;        // wave id; 4 consecutive targets
    const int gb = (wbase * 4) & ~(NPTS - 1);     // 4-aligned -> single graph

    // preload all 4 targets' neighbor rows with 2 coalesced loads
    // (lanes 0-31 = even target, lanes 32-63 = odd target)
    int nvAll[2];
    #pragma unroll
    for (int q = 0; q < 2; ++q)
        nvAll[q] = (int)nb16[(size_t)(wbase * 4 + q * 2 + (lane >> 5)) * 32 + (lane & 31)];

    for (int p = 0; p < 4; ++p) {
        const int tgt = wbase * 4 + p;
        const int nv = nvAll[p >> 1];
        const unsigned long long bm = __ballot(nv != 0xFFFF);
        const unsigned vmask = (p & 1) ? (unsigned)(bm >> 32) : (unsigned)bm;

        int jrow[2];
        #pragma unroll
        for (int mm = 0; mm < 2; ++mm) {
            const int j = __shfl(nv, (p & 1) * 32 + mm * 16 + c0);
            jrow[mm] = (j == 0xFFFF) ? 0 : j;
        }

        // ---- gather X (bf16 rows: ONE 16B load per fragment) ----
        bf16x8 X1[2][3];
        #pragma unroll
        for (int mm = 0; mm < 2; ++mm) {
            const short* xr = xb + (size_t)(gb + jrow[mm]) * 64;
            #pragma unroll
            for (int s = 0; s < 2; ++s)
                X1[mm][s] = *(const bf16x8*)(xr + s * 32 + kg * 8);
            bf16x8 a = {0, 0, 0, 0, 0, 0, 0, 0};
            if (kg == 0) {
                const float* pj = pos + (size_t)(gb + jrow[mm]) * 3;
                const float* pi = pos + (size_t)tgt * 3;
                a[0] = bfc(pj[0] - pi[0]);
                a[1] = bfc(pj[1] - pi[1]);
                a[2] = bfc(pj[2] - pi[2]);
            }
            X1[mm][2] = a;
        }

        // ---- layer 1 (swapped): h1 channel = nt*16 + kg*4 + r, col = neighbor ----
        bf16x8 B2[2][2];
        #pragma unroll
        for (int nt = 0; nt < 4; ++nt) {
            const float4 bb = *(const float4*)(b1 + nt * 16 + rlow);
            f32x4 acc[2];
            acc[0] = acc[1] = f32x4{bb.x, bb.y, bb.z, bb.w};
            #pragma unroll
            for (int s = 0; s < 3; ++s) {
                const bf16x8 Wf = *(const bf16x8*)(bfr + (size_t)((s * 4 + nt) * 64 + lane) * 8);
                #pragma unroll
                for (int mm = 0; mm < 2; ++mm)
                    acc[mm] = MFMA_BF16(Wf, X1[mm][s], acc[mm], 0, 0, 0);
            }
            // in-lane relu+cvt into next B-frag (sigma order): nt -> (s=nt>>1, j=(nt&1)*4+r)
            #pragma unroll
            for (int mm = 0; mm < 2; ++mm)
                #pragma unroll
                for (int r = 0; r < 4; ++r)
                    B2[mm][nt >> 1][(nt & 1) * 4 + r] = bfc(fmaxf(acc[mm][r], 0.f));
            SCHED_FENCE();   // bound live set: one nt's Wf + acc in flight
        }

        // ---- layer 2 (swapped, sigma-packed W2) ----
        bf16x8 A3[2][2];
        #pragma unroll
        for (int nt = 0; nt < 4; ++nt) {
            const float4 bb = *(const float4*)(b2 + nt * 16 + rlow);
            f32x4 acc[2];
            acc[0] = acc[1] = f32x4{bb.x, bb.y, bb.z, bb.w};
            #pragma unroll
            for (int s = 0; s < 2; ++s) {
                const bf16x8 Wf = *(const bf16x8*)(bfr + (size_t)((12 + s * 4 + nt) * 64 + lane) * 8);
                #pragma unroll
                for (int mm = 0; mm < 2; ++mm)
                    acc[mm] = MFMA_BF16(Wf, B2[mm][s], acc[mm], 0, 0, 0);
            }
            #pragma unroll
            for (int mm = 0; mm < 2; ++mm)
                #pragma unroll
                for (int r = 0; r < 4; ++r)
                    A3[mm][nt >> 1][(nt & 1) * 4 + r] = bfc(fmaxf(acc[mm][r], 0.f));
            SCHED_FENCE();
        }

        // ---- layer 3 (un-swapped: A=h2-frag, B=sigma-packed W3) + masked max ----
        #pragma unroll
        for (int n = 0; n < 8; ++n) {
            const float bv = b3[n * 16 + c0];
            f32x4 acc[2];
            acc[0] = acc[1] = f32x4{bv, bv, bv, bv};
            #pragma unroll
            for (int s = 0; s < 2; ++s) {
                const bf16x8 Bf = *(const bf16x8*)(bfr + (size_t)((20 + s * 8 + n) * 64 + lane) * 8);
                #pragma unroll
                for (int mm = 0; mm < 2; ++mm)
                    acc[mm] = MFMA_BF16(A3[mm][s], Bf, acc[mm], 0, 0, 0);
            }
            float v = 0.f;
            #pragma unroll
            for (int mm = 0; mm < 2; ++mm)
                #pragma unroll
                for (int r = 0; r < 4; ++r) {
                    const int row = mm * 16 + rlow + r;
                    const float h = fmaxf(acc[mm][r], 0.f);
                    v = fmaxf(v, ((vmask >> row) & 1u) ? h : 0.f);
                }
            v = fmaxf(v, __shfl_xor(v, 16));
            v = fmaxf(v, __shfl_xor(v, 32));
            if (lane < 16) out[(size_t)tgt * 128 + n * 16 + lane] = v;
            SCHED_FENCE();   // bound live set: one n's Bf + acc in flight
        }

        // ---- passthrough ----
        if (lane < 3)  out[2097152 + (size_t)tgt * 3 + lane] = pos[(size_t)tgt * 3 + lane];
        if (lane == 3) out[2146304 + tgt] = (float)batch[tgt];
    }
}

extern "C" void kernel_launch(void* const* d_in, const int* in_sizes, int n_in,
                              void* d_out, int out_size, void* d_ws, size_t ws_size,
                              hipStream_t stream) {
    const float* x   = (const float*)d_in[0];
    const float* pos = (const float*)d_in[1];
    const int* batch = (const int*)d_in[2];
    const float* W1  = (const float*)d_in[3];
    const float* b1  = (const float*)d_in[4];
    const float* W2  = (const float*)d_in[5];
    const float* b2  = (const float*)d_in[6];
    const float* W3  = (const float*)d_in[7];
    const float* b3  = (const float*)d_in[8];
    float* out = (float*)d_out;

    short* xb = (short*)d_ws;                                     // 2 MiB bf16 x
    unsigned short* nb16 = (unsigned short*)((char*)d_ws + (2 << 20)); // 1 MiB
    short* frg = (short*)((char*)d_ws + (3 << 20));               // 36 KiB

    hipLaunchKernelGGL(knn_kernel, dim3(2048), dim3(256), 0, stream,
                       x, pos, W1, W2, W3, nb16, frg, xb);
    hipLaunchKernelGGL(mlp_kernel, dim3(1024), dim3(256), 0, stream,
                       xb, pos, batch, b1, b2, b3, nb16, frg, out);
}